// Round 1
// baseline (2332.802 us; speedup 1.0000x reference)
//
#include <hip/hip_runtime.h>
#include <hip/hip_bf16.h>
#include <stdint.h>

// Problem constants
#define B_  256
#define T_  500
#define I_  1024     // K
#define O_  2048     // N
#define M_  (B_ * T_)   // 128000 rows

// GEMM tiling
#define BM 128
#define BN 128
#define BK 32
#define KTILES (I_ / BK)   // 32

typedef __attribute__((ext_vector_type(8))) short bf16x8;   // 8 bf16 = 4 VGPRs
typedef __attribute__((ext_vector_type(4))) float f32x4;

__device__ __forceinline__ void async_ld16(const void* g, const void* l) {
    // global -> LDS direct copy, 16 B per lane; LDS dst = uniform base + lane*16
    __builtin_amdgcn_global_load_lds(
        (const __attribute__((address_space(1))) void*)g,
        (__attribute__((address_space(3))) void*)l,
        16, 0, 0);
}

__device__ __forceinline__ float bf2f(unsigned short u) {
    return __uint_as_float(((unsigned int)u) << 16);
}

// ---------------------------------------------------------------------------
// Kernel 1: x fp32 -> bf16 (4 elems/thread, exact division: 131072000 % 4 == 0)
// ---------------------------------------------------------------------------
__global__ __launch_bounds__(256) void convert_x_kernel(
    const float* __restrict__ x, unsigned short* __restrict__ xb)
{
    long long i = (long long)blockIdx.x * 256 + threadIdx.x;
    float4 v = ((const float4*)x)[i];
    union { ushort4 u; __hip_bfloat16 h[4]; } pk;
    pk.h[0] = __float2bfloat16(v.x);
    pk.h[1] = __float2bfloat16(v.y);
    pk.h[2] = __float2bfloat16(v.z);
    pk.h[3] = __float2bfloat16(v.w);
    ((ushort4*)xb)[i] = pk.u;
}

// ---------------------------------------------------------------------------
// Kernel 2: w [K,O] fp32 -> wT [O,K] bf16 (32x32 LDS tile transpose)
// ---------------------------------------------------------------------------
__global__ __launch_bounds__(256) void transpose_w_kernel(
    const float* __restrict__ w, unsigned short* __restrict__ wT)
{
    __shared__ float tile[32][33];
    const int tx  = threadIdx.x & 31;
    const int ty0 = threadIdx.x >> 5;            // 0..7
    const int ob  = (blockIdx.x & 63) * 32;      // O/32 = 64
    const int kb  = (blockIdx.x >> 6) * 32;      // K/32 = 32
#pragma unroll
    for (int j = 0; j < 4; ++j) {
        int ky = ty0 + j * 8;
        tile[ky][tx] = w[(long long)(kb + ky) * O_ + ob + tx];
    }
    __syncthreads();
#pragma unroll
    for (int j = 0; j < 4; ++j) {
        int oy = ty0 + j * 8;
        __hip_bfloat16 hv = __float2bfloat16(tile[tx][oy]);
        wT[(long long)(ob + oy) * I_ + kb + tx] = *(unsigned short*)&hv;
    }
}

// ---------------------------------------------------------------------------
// Kernel 3: bf16 MFMA GEMM  h[M,N] = xb[M,K] * wT[N,K]^T   (m97 structure)
// 256 threads = 4 waves; 128x128 block tile; wave computes 64x64 (4x4 MFMA
// tiles of 16x16x32). Single-buffered LDS, 2 barriers/K-step,
// global_load_lds width 16.
// ---------------------------------------------------------------------------
__global__ __launch_bounds__(256) void gemm_kernel(
    const unsigned short* __restrict__ xb,   // [M, K] bf16
    const unsigned short* __restrict__ wT,   // [N, K] bf16
    unsigned short* __restrict__ h)          // [M, N] bf16
{
    __shared__ ushort lds[BM * BK + BN * BK];   // 8 KB + 8 KB
    ushort* Al = lds;                // [128][32] bf16, row stride 64 B
    ushort* Bl = lds + BM * BK;      // [128][32] bf16 (n-major)

    const int tid  = threadIdx.x;
    const int lane = tid & 63;
    const int wv   = tid >> 6;       // 0..3
    const int wm   = wv & 1;         // M half (64)
    const int wn   = wv >> 1;        // N half (64)

    const int bid  = blockIdx.x;
    const int mb   = bid >> 4;       // 0..999  (16 consecutive blocks share A panel)
    const int nb   = bid & 15;
    const int row0 = mb * BM;
    const int col0 = nb * BN;

    // Staging: 8 chunks of 1 KB each for A and for B; wave wv does chunks
    // j = 2*wv, 2*wv+1. Chunk j covers 16 rows (j*16 + lane/4), 16 B per lane.
    const int j0   = wv * 2;
    const int lrow = lane >> 2;          // 0..15
    const int lke  = (lane & 3) * 8;     // k element offset (8 bf16 = 16 B)

    const unsigned short* gA0 = xb + (long long)(row0 + j0 * 16 + lrow) * I_ + lke;
    const unsigned short* gA1 = gA0 + 16 * I_;
    const unsigned short* gB0 = wT + (long long)(col0 + j0 * 16 + lrow) * I_ + lke;
    const unsigned short* gB1 = gB0 + 16 * I_;
    ushort* lA0 = Al + j0 * 512;     // wave-uniform LDS bases
    ushort* lA1 = lA0 + 512;
    ushort* lB0 = Bl + j0 * 512;
    ushort* lB1 = lB0 + 512;

    f32x4 acc[4][4];
#pragma unroll
    for (int mt = 0; mt < 4; ++mt)
#pragma unroll
        for (int nt = 0; nt < 4; ++nt)
            acc[mt][nt] = f32x4{0.f, 0.f, 0.f, 0.f};

    const int kq = (lane >> 4) * 8;   // fragment k offset within BK
    const int rl = lane & 15;         // fragment row/col within 16

    for (int kt = 0; kt < KTILES; ++kt) {
        __syncthreads();              // prior iter's ds_reads done before overwrite
        async_ld16(gA0, lA0);
        async_ld16(gA1, lA1);
        async_ld16(gB0, lB0);
        async_ld16(gB1, lB1);
        gA0 += BK; gA1 += BK; gB0 += BK; gB1 += BK;
        __syncthreads();              // drains vmcnt(0): LDS tiles visible

        bf16x8 af[4], bfr[4];
#pragma unroll
        for (int mt = 0; mt < 4; ++mt)
            af[mt] = *(const bf16x8*)&Al[(wm * 64 + mt * 16 + rl) * BK + kq];
#pragma unroll
        for (int nt = 0; nt < 4; ++nt)
            bfr[nt] = *(const bf16x8*)&Bl[(wn * 64 + nt * 16 + rl) * BK + kq];
#pragma unroll
        for (int mt = 0; mt < 4; ++mt)
#pragma unroll
            for (int nt = 0; nt < 4; ++nt)
                acc[mt][nt] = __builtin_amdgcn_mfma_f32_16x16x32_bf16(
                    af[mt], bfr[nt], acc[mt][nt], 0, 0, 0);
    }

    // Epilogue: verified C/D mapping col = lane&15, row = (lane>>4)*4 + reg
    const int rq = (lane >> 4) * 4;
    const int cl = lane & 15;
#pragma unroll
    for (int mt = 0; mt < 4; ++mt) {
#pragma unroll
        for (int nt = 0; nt < 4; ++nt) {
            const int col  = col0 + wn * 64 + nt * 16 + cl;
            long long base = (long long)(row0 + wm * 64 + mt * 16 + rq) * O_ + col;
#pragma unroll
            for (int r = 0; r < 4; ++r) {
                __hip_bfloat16 hv = __float2bfloat16(acc[mt][nt][r]);
                h[base + (long long)r * O_] = *(unsigned short*)&hv;
            }
        }
    }
}

// ---------------------------------------------------------------------------
// Kernel 4: leaky-integrator scan over T.
// out[b,0,:] = 0 ; out[b,t,:] = decay * out[b,t-1,:] + h[b,t-1,:]
// Thread owns (b, 4 consecutive o). 131072 threads = 512 blocks.
// ---------------------------------------------------------------------------
__global__ __launch_bounds__(256) void scan_kernel(
    const unsigned short* __restrict__ h,   // [B*T, O] bf16
    const float* __restrict__ alpha,        // [O]
    const float* __restrict__ beta,         // [O]
    float* __restrict__ out)                // [B, T, O] fp32
{
    const int tid = blockIdx.x * 256 + threadIdx.x;   // 0 .. 131071
    const int b   = tid >> 9;                         // O/4 = 512 threads per b
    const int o0  = (tid & 511) * 4;

    float4 al = *(const float4*)&alpha[o0];
    float4 be = *(const float4*)&beta[o0];
    const float d0 = al.x * (1.f - be.x);
    const float d1 = al.y * (1.f - be.y);
    const float d2 = al.z * (1.f - be.z);
    const float d3 = al.w * (1.f - be.w);

    long long obase = (long long)b * T_ * O_ + o0;
    *(float4*)&out[obase] = float4{0.f, 0.f, 0.f, 0.f};   // t = 0 row

    const unsigned short* hp = h + obase;    // h[b, 0, o0]
    float* op = out + obase + O_;            // out[b, 1, o0]
    float s0 = 0.f, s1 = 0.f, s2 = 0.f, s3 = 0.f;

    for (int t = 1; t < T_; ++t) {
        ushort4 hv = *(const ushort4*)hp;
        s0 = d0 * s0 + bf2f(hv.x);
        s1 = d1 * s1 + bf2f(hv.y);
        s2 = d2 * s2 + bf2f(hv.z);
        s3 = d3 * s3 + bf2f(hv.w);
        *(float4*)op = float4{s0, s1, s2, s3};
        hp += O_;
        op += O_;
    }
}

// ---------------------------------------------------------------------------
extern "C" void kernel_launch(void* const* d_in, const int* in_sizes, int n_in,
                              void* d_out, int out_size, void* d_ws, size_t ws_size,
                              hipStream_t stream) {
    const float* x     = (const float*)d_in[0];   // [B,T,I] = 131072000
    const float* w     = (const float*)d_in[1];   // [I,O]   = 2097152
    const float* alpha = (const float*)d_in[2];   // [O]
    const float* beta  = (const float*)d_in[3];   // [O]
    float* out = (float*)d_out;                   // [B,T,O] fp32

    // Workspace layout (all 16B-aligned):
    //   xb : 131072000 * 2 = 262,144,000 B
    //   wT :   2097152 * 2 =   4,194,304 B
    //   h  : 262144000 * 2 = 524,288,000 B   -> total ~790 MB
    char* ws = (char*)d_ws;
    unsigned short* xb = (unsigned short*)ws;
    unsigned short* wT = (unsigned short*)(ws + 262144000LL);
    unsigned short* h  = (unsigned short*)(ws + 262144000LL + 4194304LL);

    convert_x_kernel<<<131072000 / 4 / 256, 256, 0, stream>>>(x, xb);
    transpose_w_kernel<<<(O_ / 32) * (I_ / 32), 256, 0, stream>>>(w, wT);
    gemm_kernel<<<(M_ / BM) * (O_ / BN), 256, 0, stream>>>(xb, wT, h);
    scan_kernel<<<(B_ * O_ / 4) / 256, 256, 0, stream>>>(h, alpha, beta, out);
}